// Round 2
// baseline (14219.322 us; speedup 1.0000x reference)
//
#include <hip/hip_runtime.h>
#include <hip/hip_bf16.h>

constexpr int N_   = 131072;
constexpr int G_   = 4096;
constexpr int E_   = 524288;
constexpr int C_   = 96;
constexpr int L_   = 8;
constexpr int FIN_ = 64;
constexpr int TOT_ = N_ + G_;   // 135168

__device__ __forceinline__ float silu_f(float y) { return y / (1.f + __expf(-y)); }

__device__ __forceinline__ void atomAddF(float* p, float v) {
  unsafeAtomicAdd(p, v);
}
__device__ __forceinline__ void atomAddD(double* p, double v) {
  unsafeAtomicAdd(p, v);
}

// ---------------- encoder: h[:N] = x @ enc_w + enc_b ; h[N:] = vn_emb ----------------
__global__ __launch_bounds__(256) void k_encode(const float* __restrict__ x,
    const float* __restrict__ w, const float* __restrict__ b,
    const float* __restrict__ vn, float* __restrict__ h) {
  int idx = blockIdx.x * 256 + threadIdx.x;
  if (idx >= TOT_ * C_) return;
  int row = idx / C_;
  int c   = idx - row * C_;
  if (row < N_) {
    float s = b[c];
    const float* xr = x + (size_t)row * FIN_;
    #pragma unroll
    for (int k = 0; k < FIN_; ++k) s = fmaf(xr[k], w[k * C_ + c], s);
    h[idx] = s;
  } else {
    h[idx] = vn[c];
  }
}

// ---------------- agg = h + (node? h[vn(batch)] : 0) ----------------
__global__ __launch_bounds__(256) void k_agg_init(const float* __restrict__ h,
    const int* __restrict__ batch, float* __restrict__ agg) {
  int idx = blockIdx.x * 256 + threadIdx.x;
  if (idx >= TOT_ * C_) return;
  int row = idx / C_;
  int c   = idx - row * C_;
  float v = h[idx];
  if (row < N_) v += h[(size_t)(N_ + batch[row]) * C_ + c];
  agg[idx] = v;
}

// ---------------- agg[vn(batch[j])] += h[j]  (node -> virtual node) ----------------
__global__ __launch_bounds__(256) void k_vn_scatter(const float* __restrict__ h,
    const int* __restrict__ batch, float* __restrict__ agg) {
  int idx = blockIdx.x * 256 + threadIdx.x;
  if (idx >= N_ * C_) return;
  int row = idx / C_;
  int c   = idx - row * C_;
  atomAddF(&agg[(size_t)(N_ + batch[row]) * C_ + c], h[idx]);
}

// ---------------- agg[tgt[e]] += h[src[e]] for real edges ----------------
__global__ __launch_bounds__(256) void k_edge_scatter(const float* __restrict__ h,
    const int* __restrict__ src, const int* __restrict__ tgt, float* __restrict__ agg) {
  int idx = blockIdx.x * 256 + threadIdx.x;
  if (idx >= E_ * C_) return;
  int e = idx / C_;
  int c = idx - e * C_;
  atomAddF(&agg[(size_t)tgt[e] * C_ + c], h[(size_t)src[e] * C_ + c]);
}

// ---------------- generic matmul out(R,M) = A(R,K) @ W(K,M) + bias ----------------
template <int K, int M>
__global__ __launch_bounds__(256) void k_mm(const float* __restrict__ A,
    const float* __restrict__ W, const float* __restrict__ bias,
    float* __restrict__ out, int R) {
  int idx = blockIdx.x * 256 + threadIdx.x;
  if (idx >= R * M) return;
  int row = idx / M;
  int m   = idx - row * M;
  const float* ar = A + (size_t)row * K;
  float s = bias[m];
  #pragma unroll 8
  for (int k = 0; k < K; ++k) s = fmaf(ar[k], W[k * M + m], s);
  out[idx] = s;
}

// ---------------- BN stats: per-column sum & sumsq over R rows ----------------
template <int CC>
__global__ __launch_bounds__(256) void k_bnstats(const float* __restrict__ X, int R,
                                                 double* __restrict__ st) {
  int c = threadIdx.x;  // blockDim.x == CC
  float s = 0.f, q = 0.f;
  for (int r = blockIdx.x; r < R; r += gridDim.x) {
    float v = X[(size_t)r * CC + c];
    s += v;
    q += v * v;
  }
  atomAddD(&st[c], (double)s);
  atomAddD(&st[CC + c], (double)q);
}

// ---------------- finalize: scale = g*rsqrt(var+eps), shift = be - mean*scale ----------------
template <int CC>
__global__ __launch_bounds__(256) void k_bnfin(const double* __restrict__ st, int R,
    const float* __restrict__ g, const float* __restrict__ be,
    float* __restrict__ scale, float* __restrict__ shift) {
  int c = threadIdx.x;
  if (c >= CC) return;
  double mean = st[c] / R;
  double var  = st[CC + c] / R - mean * mean;
  float sc = g[c] * rsqrtf((float)var + 1e-5f);
  scale[c] = sc;
  shift[c] = be[c] - (float)mean * sc;
}

// ---------------- in-place BN + SiLU ----------------
template <int CC>
__global__ __launch_bounds__(256) void k_bnsilu(float* __restrict__ X, int R,
    const float* __restrict__ scale, const float* __restrict__ shift) {
  int idx = blockIdx.x * 256 + threadIdx.x;
  if (idx >= R * CC) return;
  int c = idx % CC;
  float y = fmaf(X[idx], scale[c], shift[c]);
  X[idx] = silu_f(y);
}

// ---------------- h = (resid ? h : 0) + silu(bn(Z)) ----------------
template <int CC>
__global__ __launch_bounds__(256) void k_update(const float* __restrict__ Z,
    float* __restrict__ h, int R, const float* __restrict__ scale,
    const float* __restrict__ shift, int addResid) {
  int idx = blockIdx.x * 256 + threadIdx.x;
  if (idx >= R * CC) return;
  int c = idx % CC;
  float y = fmaf(Z[idx], scale[c], shift[c]);
  y = silu_f(y);
  h[idx] = addResid ? (h[idx] + y) : y;
}

// ---------------- mean pool ----------------
__global__ __launch_bounds__(256) void k_pool(const float* __restrict__ h,
    const int* __restrict__ batch, float* __restrict__ pooled, float* __restrict__ counts) {
  int idx = blockIdx.x * 256 + threadIdx.x;
  if (idx >= N_ * C_) return;
  int row = idx / C_;
  int c   = idx - row * C_;
  int g = batch[row];
  atomAddF(&pooled[(size_t)g * C_ + c], h[idx]);
  if (c == 0) atomAddF(&counts[g], 1.0f);
}

__global__ __launch_bounds__(256) void k_pooldiv(float* __restrict__ pooled,
                                                 const float* __restrict__ counts) {
  int idx = blockIdx.x * 256 + threadIdx.x;
  if (idx >= G_ * C_) return;
  int g = idx / C_;
  pooled[idx] /= fmaxf(counts[g], 1.0f);
}

static inline int gblk(long n) { return (int)((n + 255) / 256); }

extern "C" void kernel_launch(void* const* d_in, const int* in_sizes, int n_in,
                              void* d_out, int out_size, void* d_ws, size_t ws_size,
                              hipStream_t stream) {
  (void)in_sizes; (void)n_in; (void)out_size; (void)ws_size;
  const float* x       = (const float*)d_in[0];
  const int*   ei      = (const int*)d_in[1];
  const int*   batch   = (const int*)d_in[2];
  const float* enc_w   = (const float*)d_in[4];
  const float* enc_b   = (const float*)d_in[5];
  const float* vn_emb  = (const float*)d_in[6];
  const float* vn_w1   = (const float*)d_in[7];
  const float* vn_b1   = (const float*)d_in[8];
  const float* vn_g1   = (const float*)d_in[9];
  const float* vn_be1  = (const float*)d_in[10];
  const float* vn_w2   = (const float*)d_in[11];
  const float* vn_b2   = (const float*)d_in[12];
  const float* conv_w1 = (const float*)d_in[13];
  const float* conv_b1 = (const float*)d_in[14];
  const float* conv_g1 = (const float*)d_in[15];
  const float* conv_be1= (const float*)d_in[16];
  const float* conv_w2 = (const float*)d_in[17];
  const float* conv_b2 = (const float*)d_in[18];
  const float* bn_g    = (const float*)d_in[19];
  const float* bn_b    = (const float*)d_in[20];
  const float* h_w1    = (const float*)d_in[21];
  const float* h_b1    = (const float*)d_in[22];
  const float* h_g1    = (const float*)d_in[23];
  const float* h_be1   = (const float*)d_in[24];
  const float* h_w2    = (const float*)d_in[25];
  const float* h_b2    = (const float*)d_in[26];
  const float* h_g2    = (const float*)d_in[27];
  const float* h_be2   = (const float*)d_in[28];
  const float* h_w3    = (const float*)d_in[29];
  const float* h_b3    = (const float*)d_in[30];
  float* out = (float*)d_out;

  const int* e_src = ei;        // edge_index[0]
  const int* e_tgt = ei + E_;   // edge_index[1]

  // ---- workspace layout (floats) ----
  float* h      = (float*)d_ws;                       // TOT*C
  float* agg    = h      + (size_t)TOT_ * C_;         // TOT*C   (reused as z2)
  float* z1     = agg    + (size_t)TOT_ * C_;         // TOT*2C
  float* vt     = z1     + (size_t)TOT_ * 2 * C_;     // G*C
  float* pooled = vt     + (size_t)G_ * C_;           // G*C
  float* counts = pooled + (size_t)G_ * C_;           // G
  float* t1     = counts + G_;                        // G*48
  float* t2     = t1     + (size_t)G_ * 48;           // G*24
  float* scale  = t2     + (size_t)G_ * 24;           // 256
  float* shift  = scale  + 256;                       // 256
  double* st    = (double*)(shift + 256);             // 384 doubles (sum, sumsq)

  // ---- encoder + virtual-node init ----
  k_encode<<<gblk((long)TOT_ * C_), 256, 0, stream>>>(x, enc_w, enc_b, vn_emb, h);

  // ---- 8 conv layers ----
  for (int i = 0; i < L_; ++i) {
    const float* w1  = conv_w1 + (size_t)i * C_ * 2 * C_;
    const float* b1  = conv_b1 + (size_t)i * 2 * C_;
    const float* g1  = conv_g1 + (size_t)i * 2 * C_;
    const float* be1 = conv_be1+ (size_t)i * 2 * C_;
    const float* w2  = conv_w2 + (size_t)i * 2 * C_ * C_;
    const float* b2  = conv_b2 + (size_t)i * C_;
    const float* bg  = bn_g    + (size_t)i * C_;
    const float* bb  = bn_b    + (size_t)i * C_;

    // z = h + segment_sum(h[src], tgt)
    k_agg_init<<<gblk((long)TOT_ * C_), 256, 0, stream>>>(h, batch, agg);
    k_vn_scatter<<<gblk((long)N_ * C_), 256, 0, stream>>>(h, batch, agg);
    k_edge_scatter<<<gblk((long)E_ * C_), 256, 0, stream>>>(h, e_src, e_tgt, agg);

    // z1 = z @ w1 + b1 ; BN ; SiLU
    k_mm<C_, 2 * C_><<<gblk((long)TOT_ * 2 * C_), 256, 0, stream>>>(agg, w1, b1, z1, TOT_);
    hipMemsetAsync(st, 0, 384 * sizeof(double), stream);
    k_bnstats<2 * C_><<<256, 2 * C_, 0, stream>>>(z1, TOT_, st);
    k_bnfin<2 * C_><<<1, 2 * C_, 0, stream>>>(st, TOT_, g1, be1, scale, shift);
    k_bnsilu<2 * C_><<<gblk((long)TOT_ * 2 * C_), 256, 0, stream>>>(z1, TOT_, scale, shift);

    // z2 = z1 @ w2 + b2 ; BN ; SiLU ; residual
    k_mm<2 * C_, C_><<<gblk((long)TOT_ * C_), 256, 0, stream>>>(z1, w2, b2, agg, TOT_);
    hipMemsetAsync(st, 0, 384 * sizeof(double), stream);
    k_bnstats<C_><<<256, C_, 0, stream>>>(agg, TOT_, st);
    k_bnfin<C_><<<1, C_, 0, stream>>>(st, TOT_, bg, bb, scale, shift);
    k_update<C_><<<gblk((long)TOT_ * C_), 256, 0, stream>>>(agg, h, TOT_, scale, shift, i > 0);

    // virtual-node MLP (layers 0..L-2)
    if (i < L_ - 1) {
      k_mm<C_, C_><<<gblk((long)G_ * C_), 256, 0, stream>>>(h + (size_t)N_ * C_, vn_w1, vn_b1, vt, G_);
      hipMemsetAsync(st, 0, 384 * sizeof(double), stream);
      k_bnstats<C_><<<32, C_, 0, stream>>>(vt, G_, st);
      k_bnfin<C_><<<1, C_, 0, stream>>>(st, G_, vn_g1, vn_be1, scale, shift);
      k_bnsilu<C_><<<gblk((long)G_ * C_), 256, 0, stream>>>(vt, G_, scale, shift);
      k_mm<C_, C_><<<gblk((long)G_ * C_), 256, 0, stream>>>(vt, vn_w2, vn_b2, h + (size_t)N_ * C_, G_);
    }
  }

  // ---- mean pool over nodes per graph ----
  hipMemsetAsync(pooled, 0, ((size_t)G_ * C_ + G_) * sizeof(float), stream);
  k_pool<<<gblk((long)N_ * C_), 256, 0, stream>>>(h, batch, pooled, counts);
  k_pooldiv<<<gblk((long)G_ * C_), 256, 0, stream>>>(pooled, counts);

  // ---- head MLP ----
  k_mm<C_, 48><<<gblk((long)G_ * 48), 256, 0, stream>>>(pooled, h_w1, h_b1, t1, G_);
  hipMemsetAsync(st, 0, 384 * sizeof(double), stream);
  k_bnstats<48><<<32, 48, 0, stream>>>(t1, G_, st);
  k_bnfin<48><<<1, 48, 0, stream>>>(st, G_, h_g1, h_be1, scale, shift);
  k_bnsilu<48><<<gblk((long)G_ * 48), 256, 0, stream>>>(t1, G_, scale, shift);

  k_mm<48, 24><<<gblk((long)G_ * 24), 256, 0, stream>>>(t1, h_w2, h_b2, t2, G_);
  hipMemsetAsync(st, 0, 384 * sizeof(double), stream);
  k_bnstats<24><<<32, 24, 0, stream>>>(t2, G_, st);
  k_bnfin<24><<<1, 24, 0, stream>>>(st, G_, h_g2, h_be2, scale, shift);
  k_bnsilu<24><<<gblk((long)G_ * 24), 256, 0, stream>>>(t2, G_, scale, shift);

  k_mm<24, 5><<<gblk((long)G_ * 5), 256, 0, stream>>>(t2, h_w3, h_b3, out, G_);
}

// Round 3
// 4762.027 us; speedup vs baseline: 2.9860x; 2.9860x over previous
//
#include <hip/hip_runtime.h>
#include <hip/hip_bf16.h>

constexpr int N_   = 131072;
constexpr int G_   = 4096;
constexpr int E_   = 524288;
constexpr int C_   = 96;
constexpr int L_   = 8;
constexpr int FIN_ = 64;
constexpr int TOT_ = N_ + G_;   // 135168

typedef __attribute__((ext_vector_type(8))) short short8v;
typedef __attribute__((ext_vector_type(4))) float f32x4;
using bf16 = __hip_bfloat16;

__device__ __forceinline__ float silu_f(float y) { return y / (1.f + __expf(-y)); }
__device__ __forceinline__ float toF(float x) { return x; }
__device__ __forceinline__ float toF(bf16 x)  { return __bfloat162float(x); }
__device__ __forceinline__ void stv(float* p, float v) { *p = v; }
__device__ __forceinline__ void stv(bf16* p, float v)  { *p = __float2bfloat16(v); }
__device__ __forceinline__ void atomAddD(double* p, double v) { unsafeAtomicAdd(p, v); }

// ======================= preprocessing =======================

// cast x (N x 64 fp32) -> bf16
__global__ __launch_bounds__(256) void k_cast_x(const float* __restrict__ x, bf16* __restrict__ xb) {
  int idx = blockIdx.x * 256 + threadIdx.x;
  if (idx >= N_ * FIN_) return;
  xb[idx] = __float2bfloat16(x[idx]);
}

// transpose L matrices of (Kd x Nd) fp32 -> (Nd x Kd) bf16 each
__global__ __launch_bounds__(256) void k_transT(const float* __restrict__ src, bf16* __restrict__ dst,
                                                int Kd, int Nd, int total) {
  int idx = blockIdx.x * 256 + threadIdx.x;
  if (idx >= total) return;
  int per = Kd * Nd;
  int i   = idx / per;
  int rem = idx - i * per;
  int k   = rem / Nd;
  int n   = rem - k * Nd;
  dst[(size_t)i * per + n * Kd + k] = __float2bfloat16(src[idx]);
}

// deg[tgt[e]]++
__global__ __launch_bounds__(256) void k_deg_count(const int* __restrict__ tgt, int* __restrict__ deg) {
  int e = blockIdx.x * 256 + threadIdx.x;
  if (e >= E_) return;
  atomicAdd(&deg[tgt[e]], 1);
}

// block-local exclusive scan (256/block) + block sums
__global__ __launch_bounds__(256) void k_scan_local(const int* __restrict__ deg, int* __restrict__ lp,
                                                    int* __restrict__ bsum) {
  __shared__ int s[256];
  int t = threadIdx.x;
  int i = blockIdx.x * 256 + t;
  int v = deg[i];
  s[t] = v;
  __syncthreads();
  for (int off = 1; off < 256; off <<= 1) {
    int x = (t >= off) ? s[t - off] : 0;
    __syncthreads();
    s[t] += x;
    __syncthreads();
  }
  lp[i] = s[t] - v;  // exclusive
  if (t == 255) bsum[blockIdx.x] = s[255];
}

// single-block scan of 512 block sums -> exclusive offsets
__global__ __launch_bounds__(512) void k_scan_bsum(const int* __restrict__ bsum, int* __restrict__ boff) {
  __shared__ int s[512];
  int t = threadIdx.x;
  int v = bsum[t];
  s[t] = v;
  __syncthreads();
  for (int off = 1; off < 512; off <<= 1) {
    int x = (t >= off) ? s[t - off] : 0;
    __syncthreads();
    s[t] += x;
    __syncthreads();
  }
  boff[t] = s[t] - v;
}

__global__ __launch_bounds__(256) void k_scan_add(int* __restrict__ rs, const int* __restrict__ boff) {
  int i = blockIdx.x * 256 + threadIdx.x;
  if (i > N_) return;
  if (i == N_) { rs[N_] = E_; return; }
  rs[i] += boff[i >> 8];
}

// ssrc[rs[t] + cursor[t]++] = src[e]
__global__ __launch_bounds__(256) void k_csr_fill(const int* __restrict__ src, const int* __restrict__ tgt,
                                                  const int* __restrict__ rs, int* __restrict__ cur,
                                                  int* __restrict__ ssrc) {
  int e = blockIdx.x * 256 + threadIdx.x;
  if (e >= E_) return;
  int t = tgt[e];
  int pos = atomicAdd(&cur[t], 1);
  ssrc[rs[t] + pos] = src[e];
}

// graph boundaries from sorted batch: gstart[g] = first node of graph g, gstart[G]=N
__global__ __launch_bounds__(256) void k_gbounds(const int* __restrict__ batch, int* __restrict__ gstart) {
  int i = blockIdx.x * 256 + threadIdx.x;
  if (i > N_) return;
  if (i == N_) {
    int last = batch[N_ - 1];
    for (int g = last + 1; g <= G_; ++g) gstart[g] = N_;
    return;
  }
  int b  = batch[i];
  int bp = (i == 0) ? -1 : batch[i - 1];
  for (int g = bp + 1; g <= b; ++g) gstart[g] = i;
}

// ======================= MFMA GEMM =======================
// out(R x NOUT) = A(R x K, bf16) @ W(K x NOUT) + bias, with Wt = W^T (NOUT x K, bf16).
// m89-verified fragment layout for mfma_f32_16x16x32_bf16.
template <int K, int NOUT, typename OutT>
__global__ __launch_bounds__(256) void k_gemm(const bf16* __restrict__ A, const bf16* __restrict__ Wt,
                                              const float* __restrict__ bias, OutT* __restrict__ out,
                                              int R) {
  constexpr int KK  = K / 32;      // k-steps
  constexpr int NT  = NOUT / 16;   // n-tiles
  constexpr int UPR = K / 8;       // uint4 units per Wt row
  constexpr int LPR = UPR + 1;     // padded (breaks bank aliasing)
  __shared__ uint4 lw[NOUT * LPR];

  const uint4* wv = (const uint4*)Wt;
  for (int u = threadIdx.x; u < NOUT * UPR; u += 256) {
    int row = u / UPR, colu = u - row * UPR;
    lw[row * LPR + colu] = wv[u];
  }
  __syncthreads();

  int wave = threadIdx.x >> 6, lane = threadIdx.x & 63;
  int m0 = (blockIdx.x * 4 + wave) * 16;
  if (m0 >= R) return;
  int lr = lane & 15, lg = lane >> 4;

  // A fragments: lane holds A[m0+lr][kk*32 + lg*8 + j], j=0..7 (contiguous)
  short8v a[KK];
  const short* Arow = (const short*)A + (size_t)(m0 + lr) * K + lg * 8;
#pragma unroll
  for (int kk = 0; kk < KK; ++kk) a[kk] = *(const short8v*)(Arow + kk * 32);

  f32x4 acc[NT];
#pragma unroll
  for (int nt = 0; nt < NT; ++nt) acc[nt] = (f32x4){0.f, 0.f, 0.f, 0.f};

#pragma unroll
  for (int nt = 0; nt < NT; ++nt) {
    const short* brow = (const short*)&lw[(nt * 16 + lr) * LPR] + lg * 8;
#pragma unroll
    for (int kk = 0; kk < KK; ++kk) {
      short8v b = *(const short8v*)(brow + kk * 32);
      acc[nt] = __builtin_amdgcn_mfma_f32_16x16x32_bf16(a[kk], b, acc[nt], 0, 0, 0);
    }
  }

  // D: row = m0 + lg*4 + r, col = nt*16 + lr
  int orow = m0 + (lg << 2);
#pragma unroll
  for (int nt = 0; nt < NT; ++nt) {
    int col = nt * 16 + lr;
    float bi = bias[col];
#pragma unroll
    for (int r = 0; r < 4; ++r) {
      stv(&out[(size_t)(orow + r) * NOUT + col], acc[nt][r] + bi);
    }
  }
}

// fill virtual-node rows of h with vn_emb
__global__ __launch_bounds__(256) void k_fill_vn(float* __restrict__ h, const float* __restrict__ vn) {
  int idx = blockIdx.x * 256 + threadIdx.x;
  if (idx >= G_ * C_) return;
  int c = idx % C_;
  h[(size_t)N_ * C_ + idx] = vn[c];
}

// ======================= per-layer aggregation (gather) =======================
// agg[t] = h[t] + (t<N ? h[vn(batch[t])] + sum_{e in CSR[t]} h[src]
//                 : sum_{i in graph} h[i])          -> bf16
__global__ __launch_bounds__(256) void k_aggregate(const float* __restrict__ h, const int* __restrict__ batch,
                                                   const int* __restrict__ rs, const int* __restrict__ ssrc,
                                                   const int* __restrict__ gstart, bf16* __restrict__ agg) {
  int idx = blockIdx.x * 256 + threadIdx.x;
  if (idx >= TOT_ * C_) return;
  int row = idx / C_;
  int c   = idx - row * C_;
  float v = h[idx];
  if (row < N_) {
    v += h[(size_t)(N_ + batch[row]) * C_ + c];
    int e0 = rs[row], e1 = rs[row + 1];
    for (int e = e0; e < e1; ++e) v += h[(size_t)ssrc[e] * C_ + c];
  } else {
    int g = row - N_;
    int i0 = gstart[g], i1 = gstart[g + 1];
    for (int i = i0; i < i1; ++i) v += h[(size_t)i * C_ + c];
  }
  agg[idx] = __float2bfloat16(v);
}

// ======================= BN / activation =======================
template <int CC, typename T>
__global__ __launch_bounds__(256) void k_bnstats(const T* __restrict__ X, int R, double* __restrict__ st) {
  int c = threadIdx.x;  // blockDim.x == CC
  float s = 0.f, q = 0.f;
  for (int r = blockIdx.x; r < R; r += gridDim.x) {
    float v = toF(X[(size_t)r * CC + c]);
    s += v;
    q += v * v;
  }
  atomAddD(&st[c], (double)s);
  atomAddD(&st[CC + c], (double)q);
}

template <int CC>
__global__ __launch_bounds__(256) void k_bnfin(const double* __restrict__ st, int R,
    const float* __restrict__ g, const float* __restrict__ be,
    float* __restrict__ scale, float* __restrict__ shift) {
  int c = threadIdx.x;
  if (c >= CC) return;
  double mean = st[c] / R;
  double var  = st[CC + c] / R - mean * mean;
  float sc = g[c] * rsqrtf((float)var + 1e-5f);
  scale[c] = sc;
  shift[c] = be[c] - (float)mean * sc;
}

template <int CC, typename T>
__global__ __launch_bounds__(256) void k_bnsilu(T* __restrict__ X, int R,
    const float* __restrict__ scale, const float* __restrict__ shift) {
  int idx = blockIdx.x * 256 + threadIdx.x;
  if (idx >= R * CC) return;
  int c = idx % CC;
  float y = fmaf(toF(X[idx]), scale[c], shift[c]);
  stv(&X[idx], silu_f(y));
}

// h = (resid ? h : 0) + silu(bn(Z))
template <int CC>
__global__ __launch_bounds__(256) void k_update(const bf16* __restrict__ Z, float* __restrict__ h, int R,
    const float* __restrict__ scale, const float* __restrict__ shift, int addResid) {
  int idx = blockIdx.x * 256 + threadIdx.x;
  if (idx >= R * CC) return;
  int c = idx % CC;
  float y = fmaf(toF(Z[idx]), scale[c], shift[c]);
  y = silu_f(y);
  h[idx] = addResid ? (h[idx] + y) : y;
}

// ======================= small fp32 matmul (VN + head) =======================
template <int K, int M>
__global__ __launch_bounds__(256) void k_mm(const float* __restrict__ A,
    const float* __restrict__ W, const float* __restrict__ bias,
    float* __restrict__ out, int R) {
  int idx = blockIdx.x * 256 + threadIdx.x;
  if (idx >= R * M) return;
  int row = idx / M;
  int m   = idx - row * M;
  const float* ar = A + (size_t)row * K;
  float s = bias[m];
#pragma unroll 8
  for (int k = 0; k < K; ++k) s = fmaf(ar[k], W[k * M + m], s);
  out[idx] = s;
}

// mean pool via sorted-batch segments
__global__ __launch_bounds__(256) void k_pool2(const float* __restrict__ h, const int* __restrict__ gstart,
                                               float* __restrict__ pooled) {
  int idx = blockIdx.x * 256 + threadIdx.x;
  if (idx >= G_ * C_) return;
  int g = idx / C_;
  int c = idx - g * C_;
  int i0 = gstart[g], i1 = gstart[g + 1];
  float s = 0.f;
  for (int i = i0; i < i1; ++i) s += h[(size_t)i * C_ + c];
  pooled[idx] = s / fmaxf((float)(i1 - i0), 1.0f);
}

static inline int gblk(long n) { return (int)((n + 255) / 256); }

extern "C" void kernel_launch(void* const* d_in, const int* in_sizes, int n_in,
                              void* d_out, int out_size, void* d_ws, size_t ws_size,
                              hipStream_t stream) {
  (void)in_sizes; (void)n_in; (void)out_size; (void)ws_size;
  const float* x       = (const float*)d_in[0];
  const int*   ei      = (const int*)d_in[1];
  const int*   batch   = (const int*)d_in[2];
  const float* enc_w   = (const float*)d_in[4];
  const float* enc_b   = (const float*)d_in[5];
  const float* vn_emb  = (const float*)d_in[6];
  const float* vn_w1   = (const float*)d_in[7];
  const float* vn_b1   = (const float*)d_in[8];
  const float* vn_g1   = (const float*)d_in[9];
  const float* vn_be1  = (const float*)d_in[10];
  const float* vn_w2   = (const float*)d_in[11];
  const float* vn_b2   = (const float*)d_in[12];
  const float* conv_w1 = (const float*)d_in[13];
  const float* conv_b1 = (const float*)d_in[14];
  const float* conv_g1 = (const float*)d_in[15];
  const float* conv_be1= (const float*)d_in[16];
  const float* conv_w2 = (const float*)d_in[17];
  const float* conv_b2 = (const float*)d_in[18];
  const float* bn_g    = (const float*)d_in[19];
  const float* bn_b    = (const float*)d_in[20];
  const float* h_w1    = (const float*)d_in[21];
  const float* h_b1    = (const float*)d_in[22];
  const float* h_g1    = (const float*)d_in[23];
  const float* h_be1   = (const float*)d_in[24];
  const float* h_w2    = (const float*)d_in[25];
  const float* h_b2    = (const float*)d_in[26];
  const float* h_g2    = (const float*)d_in[27];
  const float* h_be2   = (const float*)d_in[28];
  const float* h_w3    = (const float*)d_in[29];
  const float* h_b3    = (const float*)d_in[30];
  float* out = (float*)d_out;

  const int* e_src = ei;        // edge_index[0]
  const int* e_tgt = ei + E_;   // edge_index[1]

  // ---- workspace bump allocator (16B aligned chunks) ----
  char* p = (char*)d_ws;
  auto alloc = [&](size_t bytes) -> char* {
    char* r = p;
    p += (bytes + 15) & ~size_t(15);
    return r;
  };
  float*  h      = (float*) alloc((size_t)TOT_ * C_ * 4);
  float*  vt     = (float*) alloc((size_t)G_ * C_ * 4);
  float*  pooled = (float*) alloc((size_t)G_ * C_ * 4);
  float*  t1     = (float*) alloc((size_t)G_ * 48 * 4);
  float*  t2     = (float*) alloc((size_t)G_ * 24 * 4);
  float*  scale  = (float*) alloc(256 * 4);
  float*  shift  = (float*) alloc(256 * 4);
  double* st     = (double*)alloc(384 * 8);
  bf16*   agg    = (bf16*)  alloc((size_t)TOT_ * C_ * 2);
  bf16*   z1     = (bf16*)  alloc((size_t)TOT_ * 2 * C_ * 2);
  bf16*   z2     = (bf16*)  alloc((size_t)TOT_ * C_ * 2);
  bf16*   xb     = (bf16*)  alloc((size_t)N_ * FIN_ * 2);
  bf16*   encwT  = (bf16*)  alloc((size_t)C_ * FIN_ * 2);
  bf16*   w1T    = (bf16*)  alloc((size_t)L_ * 2 * C_ * C_ * 2);
  bf16*   w2T    = (bf16*)  alloc((size_t)L_ * C_ * 2 * C_ * 2);
  int*    deg    = (int*)   alloc((size_t)N_ * 4);
  int*    cur    = (int*)   alloc((size_t)N_ * 4);
  int*    rs     = (int*)   alloc((size_t)(N_ + 1) * 4);
  int*    bsum   = (int*)   alloc(512 * 4);
  int*    boff   = (int*)   alloc(512 * 4);
  int*    ssrc   = (int*)   alloc((size_t)E_ * 4);
  int*    gstart = (int*)   alloc((size_t)(G_ + 1) * 4);

  // ---- preprocessing: casts, weight transposes, CSR, graph bounds ----
  k_cast_x<<<gblk((long)N_ * FIN_), 256, 0, stream>>>(x, xb);
  k_transT<<<gblk((long)FIN_ * C_), 256, 0, stream>>>(enc_w, encwT, FIN_, C_, FIN_ * C_);
  k_transT<<<gblk((long)L_ * C_ * 2 * C_), 256, 0, stream>>>(conv_w1, w1T, C_, 2 * C_, L_ * C_ * 2 * C_);
  k_transT<<<gblk((long)L_ * 2 * C_ * C_), 256, 0, stream>>>(conv_w2, w2T, 2 * C_, C_, L_ * 2 * C_ * C_);

  hipMemsetAsync(deg, 0, (size_t)N_ * 4, stream);
  hipMemsetAsync(cur, 0, (size_t)N_ * 4, stream);
  k_deg_count<<<gblk(E_), 256, 0, stream>>>(e_tgt, deg);
  k_scan_local<<<N_ / 256, 256, 0, stream>>>(deg, rs, bsum);
  k_scan_bsum<<<1, 512, 0, stream>>>(bsum, boff);
  k_scan_add<<<gblk(N_ + 1), 256, 0, stream>>>(rs, boff);
  k_csr_fill<<<gblk(E_), 256, 0, stream>>>(e_src, e_tgt, rs, cur, ssrc);
  k_gbounds<<<gblk(N_ + 1), 256, 0, stream>>>(batch, gstart);

  // ---- encoder + VN init ----
  k_gemm<FIN_, C_, float><<<N_ / 64, 256, 0, stream>>>(xb, encwT, enc_b, h, N_);
  k_fill_vn<<<gblk((long)G_ * C_), 256, 0, stream>>>(h, vn_emb);

  // ---- 8 conv layers ----
  for (int i = 0; i < L_; ++i) {
    const bf16*  wt1 = w1T + (size_t)i * 2 * C_ * C_;
    const bf16*  wt2 = w2T + (size_t)i * C_ * 2 * C_;
    const float* b1  = conv_b1 + (size_t)i * 2 * C_;
    const float* g1  = conv_g1 + (size_t)i * 2 * C_;
    const float* be1 = conv_be1+ (size_t)i * 2 * C_;
    const float* b2  = conv_b2 + (size_t)i * C_;
    const float* bg  = bn_g    + (size_t)i * C_;
    const float* bb  = bn_b    + (size_t)i * C_;

    // z = h + segment_sum(h[src], tgt)   (pure gather)
    k_aggregate<<<gblk((long)TOT_ * C_), 256, 0, stream>>>(h, batch, rs, ssrc, gstart, agg);

    // z1 = z @ w1 + b1 ; BN ; SiLU
    k_gemm<C_, 2 * C_, bf16><<<TOT_ / 64, 256, 0, stream>>>(agg, wt1, b1, z1, TOT_);
    hipMemsetAsync(st, 0, 384 * sizeof(double), stream);
    k_bnstats<2 * C_, bf16><<<256, 2 * C_, 0, stream>>>(z1, TOT_, st);
    k_bnfin<2 * C_><<<1, 2 * C_, 0, stream>>>(st, TOT_, g1, be1, scale, shift);
    k_bnsilu<2 * C_, bf16><<<gblk((long)TOT_ * 2 * C_), 256, 0, stream>>>(z1, TOT_, scale, shift);

    // z2 = z1 @ w2 + b2 ; BN ; SiLU ; residual
    k_gemm<2 * C_, C_, bf16><<<TOT_ / 64, 256, 0, stream>>>(z1, wt2, b2, z2, TOT_);
    hipMemsetAsync(st, 0, 384 * sizeof(double), stream);
    k_bnstats<C_, bf16><<<256, C_, 0, stream>>>(z2, TOT_, st);
    k_bnfin<C_><<<1, C_, 0, stream>>>(st, TOT_, bg, bb, scale, shift);
    k_update<C_><<<gblk((long)TOT_ * C_), 256, 0, stream>>>(z2, h, TOT_, scale, shift, i > 0);

    // virtual-node MLP (layers 0..L-2)
    if (i < L_ - 1) {
      k_mm<C_, C_><<<gblk((long)G_ * C_), 256, 0, stream>>>(h + (size_t)N_ * C_, vn_w1, vn_b1, vt, G_);
      hipMemsetAsync(st, 0, 384 * sizeof(double), stream);
      k_bnstats<C_, float><<<32, C_, 0, stream>>>(vt, G_, st);
      k_bnfin<C_><<<1, C_, 0, stream>>>(st, G_, vn_g1, vn_be1, scale, shift);
      k_bnsilu<C_, float><<<gblk((long)G_ * C_), 256, 0, stream>>>(vt, G_, scale, shift);
      k_mm<C_, C_><<<gblk((long)G_ * C_), 256, 0, stream>>>(vt, vn_w2, vn_b2, h + (size_t)N_ * C_, G_);
    }
  }

  // ---- mean pool (contiguous segments, no atomics) ----
  k_pool2<<<gblk((long)G_ * C_), 256, 0, stream>>>(h, gstart, pooled);

  // ---- head MLP ----
  k_mm<C_, 48><<<gblk((long)G_ * 48), 256, 0, stream>>>(pooled, h_w1, h_b1, t1, G_);
  hipMemsetAsync(st, 0, 384 * sizeof(double), stream);
  k_bnstats<48, float><<<32, 48, 0, stream>>>(t1, G_, st);
  k_bnfin<48><<<1, 48, 0, stream>>>(st, G_, h_g1, h_be1, scale, shift);
  k_bnsilu<48, float><<<gblk((long)G_ * 48), 256, 0, stream>>>(t1, G_, scale, shift);

  k_mm<48, 24><<<gblk((long)G_ * 24), 256, 0, stream>>>(t1, h_w2, h_b2, t2, G_);
  hipMemsetAsync(st, 0, 384 * sizeof(double), stream);
  k_bnstats<24, float><<<32, 24, 0, stream>>>(t2, G_, st);
  k_bnfin<24><<<1, 24, 0, stream>>>(st, G_, h_g2, h_be2, scale, shift);
  k_bnsilu<24, float><<<gblk((long)G_ * 24), 256, 0, stream>>>(t2, G_, scale, shift);

  k_mm<24, 5><<<gblk((long)G_ * 5), 256, 0, stream>>>(t2, h_w3, h_b3, out, G_);
}

// Round 4
// 2541.081 us; speedup vs baseline: 5.5958x; 1.8740x over previous
//
#include <hip/hip_runtime.h>
#include <hip/hip_bf16.h>

constexpr int N_   = 131072;
constexpr int G_   = 4096;
constexpr int E_   = 524288;
constexpr int C_   = 96;
constexpr int L_   = 8;
constexpr int FIN_ = 64;
constexpr int TOT_ = N_ + G_;   // 135168 (divisible by 64)

typedef __attribute__((ext_vector_type(8))) short short8v;
typedef __attribute__((ext_vector_type(4))) float f32x4;
using bf16 = __hip_bfloat16;

__device__ __forceinline__ float silu_f(float y) { return y / (1.f + __expf(-y)); }
__device__ __forceinline__ float toF(float x) { return x; }
__device__ __forceinline__ float toF(bf16 x)  { return __bfloat162float(x); }
__device__ __forceinline__ float bfbits2f(short s) {
  return __uint_as_float(((unsigned)(unsigned short)s) << 16);
}
__device__ __forceinline__ short f2bfbits(float f) {
  bf16 b = __float2bfloat16(f);
  return *reinterpret_cast<short*>(&b);
}
__device__ __forceinline__ void stv(float* p, float v) { *p = v; }
__device__ __forceinline__ void stv(bf16* p, float v)  { *p = __float2bfloat16(v); }
__device__ __forceinline__ void atomAddD(double* p, double v) { unsafeAtomicAdd(p, v); }

// ======================= preprocessing =======================

__global__ __launch_bounds__(256) void k_cast_x(const float* __restrict__ x, bf16* __restrict__ xb) {
  int idx = blockIdx.x * 256 + threadIdx.x;
  if (idx >= N_ * FIN_) return;
  xb[idx] = __float2bfloat16(x[idx]);
}

__global__ __launch_bounds__(256) void k_transT(const float* __restrict__ src, bf16* __restrict__ dst,
                                                int Kd, int Nd, int total) {
  int idx = blockIdx.x * 256 + threadIdx.x;
  if (idx >= total) return;
  int per = Kd * Nd;
  int i   = idx / per;
  int rem = idx - i * per;
  int k   = rem / Nd;
  int n   = rem - k * Nd;
  dst[(size_t)i * per + n * Kd + k] = __float2bfloat16(src[idx]);
}

__global__ __launch_bounds__(256) void k_deg_count(const int* __restrict__ tgt, int* __restrict__ deg) {
  int e = blockIdx.x * 256 + threadIdx.x;
  if (e >= E_) return;
  atomicAdd(&deg[tgt[e]], 1);
}

__global__ __launch_bounds__(256) void k_scan_local(const int* __restrict__ deg, int* __restrict__ lp,
                                                    int* __restrict__ bsum) {
  __shared__ int s[256];
  int t = threadIdx.x;
  int i = blockIdx.x * 256 + t;
  int v = deg[i];
  s[t] = v;
  __syncthreads();
  for (int off = 1; off < 256; off <<= 1) {
    int x = (t >= off) ? s[t - off] : 0;
    __syncthreads();
    s[t] += x;
    __syncthreads();
  }
  lp[i] = s[t] - v;
  if (t == 255) bsum[blockIdx.x] = s[255];
}

__global__ __launch_bounds__(512) void k_scan_bsum(const int* __restrict__ bsum, int* __restrict__ boff) {
  __shared__ int s[512];
  int t = threadIdx.x;
  int v = bsum[t];
  s[t] = v;
  __syncthreads();
  for (int off = 1; off < 512; off <<= 1) {
    int x = (t >= off) ? s[t - off] : 0;
    __syncthreads();
    s[t] += x;
    __syncthreads();
  }
  boff[t] = s[t] - v;
}

__global__ __launch_bounds__(256) void k_scan_add(int* __restrict__ rs, const int* __restrict__ boff) {
  int i = blockIdx.x * 256 + threadIdx.x;
  if (i > N_) return;
  if (i == N_) { rs[N_] = E_; return; }
  rs[i] += boff[i >> 8];
}

__global__ __launch_bounds__(256) void k_csr_fill(const int* __restrict__ src, const int* __restrict__ tgt,
                                                  const int* __restrict__ rs, int* __restrict__ cur,
                                                  int* __restrict__ ssrc) {
  int e = blockIdx.x * 256 + threadIdx.x;
  if (e >= E_) return;
  int t = tgt[e];
  int pos = atomicAdd(&cur[t], 1);
  ssrc[rs[t] + pos] = src[e];
}

__global__ __launch_bounds__(256) void k_gbounds(const int* __restrict__ batch, int* __restrict__ gstart) {
  int i = blockIdx.x * 256 + threadIdx.x;
  if (i > N_) return;
  if (i == N_) {
    int last = batch[N_ - 1];
    for (int g = last + 1; g <= G_; ++g) gstart[g] = N_;
    return;
  }
  int b  = batch[i];
  int bp = (i == 0) ? -1 : batch[i - 1];
  for (int g = bp + 1; g <= b; ++g) gstart[g] = i;
}

// ======================= MFMA GEMM (fused BN-in / stats-out) =======================
// out(R x NOUT) = act(A) @ W + bias, Wt = W^T (NOUT x K bf16), R % 64 == 0, grid = R/64.
// INACT:  A element a -> silu(a*isc[k] + ish[k])   (BN+SiLU of previous layer)
// OSTATS: accumulate per-column sum/sumsq of the (rounded) outputs into st[0..NOUT-1], st[NOUT..]
template <int K, int NOUT, bool INACT, bool OSTATS, typename OutT>
__global__ __launch_bounds__(256) void k_gemm(const bf16* __restrict__ A, const bf16* __restrict__ Wt,
                                              const float* __restrict__ bias,
                                              const float* __restrict__ isc, const float* __restrict__ ish,
                                              OutT* __restrict__ out, double* __restrict__ st) {
  constexpr int KK  = K / 32;
  constexpr int NT  = NOUT / 16;
  constexpr int UPR = K / 8;
  constexpr int LPR = UPR + 1;
  __shared__ uint4 lw[NOUT * LPR];
  __shared__ float lsc[INACT ? K : 1];
  __shared__ float lsh[INACT ? K : 1];
  __shared__ float ssum[OSTATS ? 4 : 1][OSTATS ? NOUT : 1];
  __shared__ float sqsum[OSTATS ? 4 : 1][OSTATS ? NOUT : 1];

  const uint4* wv = (const uint4*)Wt;
  for (int u = threadIdx.x; u < NOUT * UPR; u += 256) {
    int row = u / UPR, colu = u - row * UPR;
    lw[row * LPR + colu] = wv[u];
  }
  if (INACT) {
    for (int k = threadIdx.x; k < K; k += 256) { lsc[k] = isc[k]; lsh[k] = ish[k]; }
  }
  __syncthreads();

  int wave = threadIdx.x >> 6, lane = threadIdx.x & 63;
  int m0 = (blockIdx.x * 4 + wave) * 16;
  int lr = lane & 15, lg = lane >> 4;

  short8v a[KK];
  const short* Arow = (const short*)A + (size_t)(m0 + lr) * K + lg * 8;
#pragma unroll
  for (int kk = 0; kk < KK; ++kk) {
    short8v raw = *(const short8v*)(Arow + kk * 32);
    if (INACT) {
      int kbase = kk * 32 + lg * 8;
#pragma unroll
      for (int j = 0; j < 8; ++j) {
        float f = bfbits2f(raw[j]);
        f = silu_f(fmaf(f, lsc[kbase + j], lsh[kbase + j]));
        raw[j] = f2bfbits(f);
      }
    }
    a[kk] = raw;
  }

  f32x4 acc[NT];
#pragma unroll
  for (int nt = 0; nt < NT; ++nt) acc[nt] = (f32x4){0.f, 0.f, 0.f, 0.f};

#pragma unroll
  for (int nt = 0; nt < NT; ++nt) {
    const short* brow = (const short*)&lw[(nt * 16 + lr) * LPR] + lg * 8;
#pragma unroll
    for (int kk = 0; kk < KK; ++kk) {
      short8v b = *(const short8v*)(brow + kk * 32);
      acc[nt] = __builtin_amdgcn_mfma_f32_16x16x32_bf16(a[kk], b, acc[nt], 0, 0, 0);
    }
  }

  // D: row = m0 + lg*4 + r, col = nt*16 + lr
  int orow = m0 + (lg << 2);
#pragma unroll
  for (int nt = 0; nt < NT; ++nt) {
    int col = nt * 16 + lr;
    float bi = bias[col];
    float s = 0.f, q = 0.f;
#pragma unroll
    for (int r = 0; r < 4; ++r) {
      float y = acc[nt][r] + bi;
      float yb;
      if constexpr (sizeof(OutT) == 2) {
        bf16 b = __float2bfloat16(y);
        out[(size_t)(orow + r) * NOUT + col] = b;
        yb = __bfloat162float(b);
      } else {
        out[(size_t)(orow + r) * NOUT + col] = y;
        yb = y;
      }
      if (OSTATS) { s += yb; q += yb * yb; }
    }
    if (OSTATS) {
      s += __shfl_xor(s, 16, 64); s += __shfl_xor(s, 32, 64);
      q += __shfl_xor(q, 16, 64); q += __shfl_xor(q, 32, 64);
      if (lg == 0) { ssum[wave][col] = s; sqsum[wave][col] = q; }
    }
  }
  if (OSTATS) {
    __syncthreads();
    int tid = threadIdx.x;
    if (tid < NOUT) {
      float s = ssum[0][tid] + ssum[1][tid] + ssum[2][tid] + ssum[3][tid];
      float q = sqsum[0][tid] + sqsum[1][tid] + sqsum[2][tid] + sqsum[3][tid];
      atomAddD(&st[tid], (double)s);
      atomAddD(&st[NOUT + tid], (double)q);
    }
  }
}

__global__ __launch_bounds__(256) void k_fill_vn(float* __restrict__ h, const float* __restrict__ vn) {
  int idx = blockIdx.x * 256 + threadIdx.x;
  if (idx >= G_ * C_) return;
  int c = idx % C_;
  h[(size_t)N_ * C_ + idx] = vn[c];
}

// ======================= aggregation (pure gather) =======================
__global__ __launch_bounds__(256) void k_aggregate(const float* __restrict__ h, const int* __restrict__ batch,
                                                   const int* __restrict__ rs, const int* __restrict__ ssrc,
                                                   const int* __restrict__ gstart, bf16* __restrict__ agg) {
  int idx = blockIdx.x * 256 + threadIdx.x;
  if (idx >= TOT_ * C_) return;
  int row = idx / C_;
  int c   = idx - row * C_;
  float v = h[idx];
  if (row < N_) {
    v += h[(size_t)(N_ + batch[row]) * C_ + c];
    int e0 = rs[row], e1 = rs[row + 1];
    for (int e = e0; e < e1; ++e) v += h[(size_t)ssrc[e] * C_ + c];
  } else {
    int g = row - N_;
    int i0 = gstart[g], i1 = gstart[g + 1];
    for (int i = i0; i < i1; ++i) v += h[(size_t)i * C_ + c];
  }
  agg[idx] = __float2bfloat16(v);
}

// ======================= BN helpers (VN / head only) =======================
template <int CC, typename T>
__global__ __launch_bounds__(256) void k_bnstats(const T* __restrict__ X, int R, double* __restrict__ st) {
  int c = threadIdx.x;
  float s = 0.f, q = 0.f;
  for (int r = blockIdx.x; r < R; r += gridDim.x) {
    float v = toF(X[(size_t)r * CC + c]);
    s += v;
    q += v * v;
  }
  atomAddD(&st[c], (double)s);
  atomAddD(&st[CC + c], (double)q);
}

template <int CC>
__global__ __launch_bounds__(256) void k_bnfin(const double* __restrict__ st, int R,
    const float* __restrict__ g, const float* __restrict__ be,
    float* __restrict__ scale, float* __restrict__ shift) {
  int c = threadIdx.x;
  if (c >= CC) return;
  double mean = st[c] / R;
  double var  = st[CC + c] / R - mean * mean;
  float sc = g[c] * rsqrtf((float)var + 1e-5f);
  scale[c] = sc;
  shift[c] = be[c] - (float)mean * sc;
}

template <int CC, typename T>
__global__ __launch_bounds__(256) void k_bnsilu(T* __restrict__ X, int R,
    const float* __restrict__ scale, const float* __restrict__ shift) {
  int idx = blockIdx.x * 256 + threadIdx.x;
  if (idx >= R * CC) return;
  int c = idx % CC;
  float y = fmaf(toF(X[idx]), scale[c], shift[c]);
  stv(&X[idx], silu_f(y));
}

// h = (resid ? h : 0) + silu(bn(Z)), 4 elements/thread
__global__ __launch_bounds__(256) void k_update(const bf16* __restrict__ Z, float* __restrict__ h,
    const float* __restrict__ scale, const float* __restrict__ shift, int addResid) {
  int idx = blockIdx.x * 256 + threadIdx.x;
  if (idx >= TOT_ * C_ / 4) return;
  int cg = idx % (C_ / 4);
  int c0 = cg * 4;
  short4 zv = ((const short4*)Z)[idx];
  float4 hv;
  if (addResid) hv = ((const float4*)h)[idx];
  float y0 = silu_f(fmaf(bfbits2f(zv.x), scale[c0 + 0], shift[c0 + 0]));
  float y1 = silu_f(fmaf(bfbits2f(zv.y), scale[c0 + 1], shift[c0 + 1]));
  float y2 = silu_f(fmaf(bfbits2f(zv.z), scale[c0 + 2], shift[c0 + 2]));
  float y3 = silu_f(fmaf(bfbits2f(zv.w), scale[c0 + 3], shift[c0 + 3]));
  float4 o;
  o.x = addResid ? hv.x + y0 : y0;
  o.y = addResid ? hv.y + y1 : y1;
  o.z = addResid ? hv.z + y2 : y2;
  o.w = addResid ? hv.w + y3 : y3;
  ((float4*)h)[idx] = o;
}

// ======================= small fp32 matmul (VN + head) =======================
template <int K, int M>
__global__ __launch_bounds__(256) void k_mm(const float* __restrict__ A,
    const float* __restrict__ W, const float* __restrict__ bias,
    float* __restrict__ out, int R) {
  int idx = blockIdx.x * 256 + threadIdx.x;
  if (idx >= R * M) return;
  int row = idx / M;
  int m   = idx - row * M;
  const float* ar = A + (size_t)row * K;
  float s = bias[m];
#pragma unroll 8
  for (int k = 0; k < K; ++k) s = fmaf(ar[k], W[k * M + m], s);
  out[idx] = s;
}

__global__ __launch_bounds__(256) void k_pool2(const float* __restrict__ h, const int* __restrict__ gstart,
                                               float* __restrict__ pooled) {
  int idx = blockIdx.x * 256 + threadIdx.x;
  if (idx >= G_ * C_) return;
  int g = idx / C_;
  int c = idx - g * C_;
  int i0 = gstart[g], i1 = gstart[g + 1];
  float s = 0.f;
  for (int i = i0; i < i1; ++i) s += h[(size_t)i * C_ + c];
  pooled[idx] = s / fmaxf((float)(i1 - i0), 1.0f);
}

static inline int gblk(long n) { return (int)((n + 255) / 256); }

extern "C" void kernel_launch(void* const* d_in, const int* in_sizes, int n_in,
                              void* d_out, int out_size, void* d_ws, size_t ws_size,
                              hipStream_t stream) {
  (void)in_sizes; (void)n_in; (void)out_size; (void)ws_size;
  const float* x       = (const float*)d_in[0];
  const int*   ei      = (const int*)d_in[1];
  const int*   batch   = (const int*)d_in[2];
  const float* enc_w   = (const float*)d_in[4];
  const float* enc_b   = (const float*)d_in[5];
  const float* vn_emb  = (const float*)d_in[6];
  const float* vn_w1   = (const float*)d_in[7];
  const float* vn_b1   = (const float*)d_in[8];
  const float* vn_g1   = (const float*)d_in[9];
  const float* vn_be1  = (const float*)d_in[10];
  const float* vn_w2   = (const float*)d_in[11];
  const float* vn_b2   = (const float*)d_in[12];
  const float* conv_w1 = (const float*)d_in[13];
  const float* conv_b1 = (const float*)d_in[14];
  const float* conv_g1 = (const float*)d_in[15];
  const float* conv_be1= (const float*)d_in[16];
  const float* conv_w2 = (const float*)d_in[17];
  const float* conv_b2 = (const float*)d_in[18];
  const float* bn_g    = (const float*)d_in[19];
  const float* bn_b    = (const float*)d_in[20];
  const float* h_w1    = (const float*)d_in[21];
  const float* h_b1    = (const float*)d_in[22];
  const float* h_g1    = (const float*)d_in[23];
  const float* h_be1   = (const float*)d_in[24];
  const float* h_w2    = (const float*)d_in[25];
  const float* h_b2    = (const float*)d_in[26];
  const float* h_g2    = (const float*)d_in[27];
  const float* h_be2   = (const float*)d_in[28];
  const float* h_w3    = (const float*)d_in[29];
  const float* h_b3    = (const float*)d_in[30];
  float* out = (float*)d_out;

  const int* e_src = ei;
  const int* e_tgt = ei + E_;

  char* p = (char*)d_ws;
  auto alloc = [&](size_t bytes) -> char* {
    char* r = p;
    p += (bytes + 15) & ~size_t(15);
    return r;
  };
  float*  h      = (float*) alloc((size_t)TOT_ * C_ * 4);
  float*  vt     = (float*) alloc((size_t)G_ * C_ * 4);
  float*  pooled = (float*) alloc((size_t)G_ * C_ * 4);
  float*  t1     = (float*) alloc((size_t)G_ * 48 * 4);
  float*  t2     = (float*) alloc((size_t)G_ * 24 * 4);
  float*  scale1 = (float*) alloc(256 * 4);
  float*  shift1 = (float*) alloc(256 * 4);
  float*  scale2 = (float*) alloc(256 * 4);
  float*  shift2 = (float*) alloc(256 * 4);
  double* st     = (double*)alloc(512 * 8);
  bf16*   agg    = (bf16*)  alloc((size_t)TOT_ * C_ * 2);
  bf16*   z1     = (bf16*)  alloc((size_t)TOT_ * 2 * C_ * 2);
  bf16*   z2     = (bf16*)  alloc((size_t)TOT_ * C_ * 2);
  bf16*   xb     = (bf16*)  alloc((size_t)N_ * FIN_ * 2);
  bf16*   encwT  = (bf16*)  alloc((size_t)C_ * FIN_ * 2);
  bf16*   w1T    = (bf16*)  alloc((size_t)L_ * 2 * C_ * C_ * 2);
  bf16*   w2T    = (bf16*)  alloc((size_t)L_ * C_ * 2 * C_ * 2);
  int*    deg    = (int*)   alloc((size_t)N_ * 4);
  int*    cur    = (int*)   alloc((size_t)N_ * 4);
  int*    rs     = (int*)   alloc((size_t)(N_ + 1) * 4);
  int*    bsum   = (int*)   alloc(512 * 4);
  int*    boff   = (int*)   alloc(512 * 4);
  int*    ssrc   = (int*)   alloc((size_t)E_ * 4);
  int*    gstart = (int*)   alloc((size_t)(G_ + 1) * 4);

  // ---- preprocessing ----
  k_cast_x<<<gblk((long)N_ * FIN_), 256, 0, stream>>>(x, xb);
  k_transT<<<gblk((long)FIN_ * C_), 256, 0, stream>>>(enc_w, encwT, FIN_, C_, FIN_ * C_);
  k_transT<<<gblk((long)L_ * C_ * 2 * C_), 256, 0, stream>>>(conv_w1, w1T, C_, 2 * C_, L_ * C_ * 2 * C_);
  k_transT<<<gblk((long)L_ * 2 * C_ * C_), 256, 0, stream>>>(conv_w2, w2T, 2 * C_, C_, L_ * 2 * C_ * C_);

  hipMemsetAsync(deg, 0, (size_t)N_ * 4, stream);
  hipMemsetAsync(cur, 0, (size_t)N_ * 4, stream);
  k_deg_count<<<gblk(E_), 256, 0, stream>>>(e_tgt, deg);
  k_scan_local<<<N_ / 256, 256, 0, stream>>>(deg, rs, bsum);
  k_scan_bsum<<<1, 512, 0, stream>>>(bsum, boff);
  k_scan_add<<<gblk(N_ + 1), 256, 0, stream>>>(rs, boff);
  k_csr_fill<<<gblk(E_), 256, 0, stream>>>(e_src, e_tgt, rs, cur, ssrc);
  k_gbounds<<<gblk(N_ + 1), 256, 0, stream>>>(batch, gstart);

  // ---- encoder + VN init ----
  k_gemm<FIN_, C_, false, false, float><<<N_ / 64, 256, 0, stream>>>(
      xb, encwT, enc_b, nullptr, nullptr, h, nullptr);
  k_fill_vn<<<gblk((long)G_ * C_), 256, 0, stream>>>(h, vn_emb);

  // ---- 8 conv layers ----
  for (int i = 0; i < L_; ++i) {
    const bf16*  wt1 = w1T + (size_t)i * 2 * C_ * C_;
    const bf16*  wt2 = w2T + (size_t)i * C_ * 2 * C_;
    const float* b1  = conv_b1 + (size_t)i * 2 * C_;
    const float* g1  = conv_g1 + (size_t)i * 2 * C_;
    const float* be1 = conv_be1+ (size_t)i * 2 * C_;
    const float* b2  = conv_b2 + (size_t)i * C_;
    const float* bg  = bn_g    + (size_t)i * C_;
    const float* bb  = bn_b    + (size_t)i * C_;

    k_aggregate<<<gblk((long)TOT_ * C_), 256, 0, stream>>>(h, batch, rs, ssrc, gstart, agg);

    // z1 = agg @ w1 + b1  (stats fused)
    hipMemsetAsync(st, 0, 384 * sizeof(double), stream);
    k_gemm<C_, 2 * C_, false, true, bf16><<<TOT_ / 64, 256, 0, stream>>>(
        agg, wt1, b1, nullptr, nullptr, z1, st);
    k_bnfin<2 * C_><<<1, 2 * C_, 0, stream>>>(st, TOT_, g1, be1, scale1, shift1);

    // z2 = silu(bn(z1)) @ w2 + b2  (BN+SiLU fused on input, stats fused on output)
    hipMemsetAsync(st, 0, 384 * sizeof(double), stream);
    k_gemm<2 * C_, C_, true, true, bf16><<<TOT_ / 64, 256, 0, stream>>>(
        z1, wt2, b2, scale1, shift1, z2, st);
    k_bnfin<C_><<<1, C_, 0, stream>>>(st, TOT_, bg, bb, scale2, shift2);

    k_update<<<gblk((long)TOT_ * C_ / 4), 256, 0, stream>>>(z2, h, scale2, shift2, i > 0);

    if (i < L_ - 1) {
      k_mm<C_, C_><<<gblk((long)G_ * C_), 256, 0, stream>>>(h + (size_t)N_ * C_, vn_w1, vn_b1, vt, G_);
      hipMemsetAsync(st, 0, 384 * sizeof(double), stream);
      k_bnstats<C_, float><<<64, C_, 0, stream>>>(vt, G_, st);
      k_bnfin<C_><<<1, C_, 0, stream>>>(st, G_, vn_g1, vn_be1, scale1, shift1);
      k_bnsilu<C_, float><<<gblk((long)G_ * C_), 256, 0, stream>>>(vt, G_, scale1, shift1);
      k_mm<C_, C_><<<gblk((long)G_ * C_), 256, 0, stream>>>(vt, vn_w2, vn_b2, h + (size_t)N_ * C_, G_);
    }
  }

  // ---- mean pool ----
  k_pool2<<<gblk((long)G_ * C_), 256, 0, stream>>>(h, gstart, pooled);

  // ---- head MLP ----
  k_mm<C_, 48><<<gblk((long)G_ * 48), 256, 0, stream>>>(pooled, h_w1, h_b1, t1, G_);
  hipMemsetAsync(st, 0, 384 * sizeof(double), stream);
  k_bnstats<48, float><<<64, 48, 0, stream>>>(t1, G_, st);
  k_bnfin<48><<<1, 48, 0, stream>>>(st, G_, h_g1, h_be1, scale1, shift1);
  k_bnsilu<48, float><<<gblk((long)G_ * 48), 256, 0, stream>>>(t1, G_, scale1, shift1);

  k_mm<48, 24><<<gblk((long)G_ * 24), 256, 0, stream>>>(t1, h_w2, h_b2, t2, G_);
  hipMemsetAsync(st, 0, 384 * sizeof(double), stream);
  k_bnstats<24, float><<<64, 24, 0, stream>>>(t2, G_, st);
  k_bnfin<24><<<1, 24, 0, stream>>>(st, G_, h_g2, h_be2, scale1, shift1);
  k_bnsilu<24, float><<<gblk((long)G_ * 24), 256, 0, stream>>>(t2, G_, scale1, shift1);

  k_mm<24, 5><<<gblk((long)G_ * 5), 256, 0, stream>>>(t2, h_w3, h_b3, out, G_);
}

// Round 5
// 1894.360 us; speedup vs baseline: 7.5061x; 1.3414x over previous
//
#include <hip/hip_runtime.h>
#include <hip/hip_bf16.h>

constexpr int N_   = 131072;
constexpr int G_   = 4096;
constexpr int E_   = 524288;
constexpr int C_   = 96;
constexpr int L_   = 8;
constexpr int FIN_ = 64;
constexpr int TOT_ = N_ + G_;   // 135168 (divisible by 64; N_/16 integral -> waves never straddle N_)

typedef __attribute__((ext_vector_type(8))) short short8v;
typedef __attribute__((ext_vector_type(4))) float f32x4;
using bf16 = __hip_bfloat16;

__device__ __forceinline__ float silu_f(float y) { return y / (1.f + __expf(-y)); }
__device__ __forceinline__ float toF(float x) { return x; }
__device__ __forceinline__ float toF(bf16 x)  { return __bfloat162float(x); }
__device__ __forceinline__ float bfbits2f(short s) {
  return __uint_as_float(((unsigned)(unsigned short)s) << 16);
}
__device__ __forceinline__ short f2bfbits(float f) {
  bf16 b = __float2bfloat16(f);
  return *reinterpret_cast<short*>(&b);
}
__device__ __forceinline__ void stv(float* p, float v) { *p = v; }
__device__ __forceinline__ void stv(bf16* p, float v)  { *p = __float2bfloat16(v); }
__device__ __forceinline__ void atomAddD(double* p, double v) { unsafeAtomicAdd(p, v); }

// ======================= preprocessing =======================

__global__ __launch_bounds__(256) void k_cast_x(const float* __restrict__ x, bf16* __restrict__ xb) {
  int idx = blockIdx.x * 256 + threadIdx.x;
  if (idx >= N_ * FIN_) return;
  xb[idx] = __float2bfloat16(x[idx]);
}

__global__ __launch_bounds__(256) void k_transT(const float* __restrict__ src, bf16* __restrict__ dst,
                                                int Kd, int Nd, int total) {
  int idx = blockIdx.x * 256 + threadIdx.x;
  if (idx >= total) return;
  int per = Kd * Nd;
  int i   = idx / per;
  int rem = idx - i * per;
  int k   = rem / Nd;
  int n   = rem - k * Nd;
  dst[(size_t)i * per + n * Kd + k] = __float2bfloat16(src[idx]);
}

__global__ __launch_bounds__(256) void k_deg_count(const int* __restrict__ tgt, int* __restrict__ deg) {
  int e = blockIdx.x * 256 + threadIdx.x;
  if (e >= E_) return;
  atomicAdd(&deg[tgt[e]], 1);
}

__global__ __launch_bounds__(256) void k_scan_local(const int* __restrict__ deg, int* __restrict__ lp,
                                                    int* __restrict__ bsum) {
  __shared__ int s[256];
  int t = threadIdx.x;
  int i = blockIdx.x * 256 + t;
  int v = deg[i];
  s[t] = v;
  __syncthreads();
  for (int off = 1; off < 256; off <<= 1) {
    int x = (t >= off) ? s[t - off] : 0;
    __syncthreads();
    s[t] += x;
    __syncthreads();
  }
  lp[i] = s[t] - v;
  if (t == 255) bsum[blockIdx.x] = s[255];
}

__global__ __launch_bounds__(512) void k_scan_bsum(const int* __restrict__ bsum, int* __restrict__ boff) {
  __shared__ int s[512];
  int t = threadIdx.x;
  int v = bsum[t];
  s[t] = v;
  __syncthreads();
  for (int off = 1; off < 512; off <<= 1) {
    int x = (t >= off) ? s[t - off] : 0;
    __syncthreads();
    s[t] += x;
    __syncthreads();
  }
  boff[t] = s[t] - v;
}

__global__ __launch_bounds__(256) void k_scan_add(int* __restrict__ rs, const int* __restrict__ boff) {
  int i = blockIdx.x * 256 + threadIdx.x;
  if (i > N_) return;
  if (i == N_) { rs[N_] = E_; return; }
  rs[i] += boff[i >> 8];
}

__global__ __launch_bounds__(256) void k_csr_fill(const int* __restrict__ src, const int* __restrict__ tgt,
                                                  const int* __restrict__ rs, int* __restrict__ cur,
                                                  int* __restrict__ ssrc) {
  int e = blockIdx.x * 256 + threadIdx.x;
  if (e >= E_) return;
  int t = tgt[e];
  int pos = atomicAdd(&cur[t], 1);
  ssrc[rs[t] + pos] = src[e];
}

__global__ __launch_bounds__(256) void k_gbounds(const int* __restrict__ batch, int* __restrict__ gstart) {
  int i = blockIdx.x * 256 + threadIdx.x;
  if (i > N_) return;
  if (i == N_) {
    int last = batch[N_ - 1];
    for (int g = last + 1; g <= G_; ++g) gstart[g] = N_;
    return;
  }
  int b  = batch[i];
  int bp = (i == 0) ? -1 : batch[i - 1];
  for (int g = bp + 1; g <= b; ++g) gstart[g] = i;
}

// ======================= MFMA GEMM (generic; fused BN-in / stats-out / bf16 shadow) =======================
template <int K, int NOUT, bool INACT, bool OSTATS, bool BFC, typename OutT>
__global__ __launch_bounds__(256) void k_gemm(const bf16* __restrict__ A, const bf16* __restrict__ Wt,
                                              const float* __restrict__ bias,
                                              const float* __restrict__ isc, const float* __restrict__ ish,
                                              OutT* __restrict__ out, bf16* __restrict__ out_bf,
                                              double* __restrict__ st) {
  constexpr int KK  = K / 32;
  constexpr int NT  = NOUT / 16;
  constexpr int UPR = K / 8;
  constexpr int LPR = UPR + 1;
  __shared__ uint4 lw[NOUT * LPR];
  __shared__ float lsc[INACT ? K : 1];
  __shared__ float lsh[INACT ? K : 1];
  __shared__ float ssum[OSTATS ? 4 : 1][OSTATS ? NOUT : 1];
  __shared__ float sqsum[OSTATS ? 4 : 1][OSTATS ? NOUT : 1];

  const uint4* wv = (const uint4*)Wt;
  for (int u = threadIdx.x; u < NOUT * UPR; u += 256) {
    int row = u / UPR, colu = u - row * UPR;
    lw[row * LPR + colu] = wv[u];
  }
  if (INACT) {
    for (int k = threadIdx.x; k < K; k += 256) { lsc[k] = isc[k]; lsh[k] = ish[k]; }
  }
  __syncthreads();

  int wave = threadIdx.x >> 6, lane = threadIdx.x & 63;
  int m0 = (blockIdx.x * 4 + wave) * 16;
  int lr = lane & 15, lg = lane >> 4;

  short8v a[KK];
  const short* Arow = (const short*)A + (size_t)(m0 + lr) * K + lg * 8;
#pragma unroll
  for (int kk = 0; kk < KK; ++kk) {
    short8v raw = *(const short8v*)(Arow + kk * 32);
    if (INACT) {
      int kbase = kk * 32 + lg * 8;
#pragma unroll
      for (int j = 0; j < 8; ++j) {
        float f = bfbits2f(raw[j]);
        f = silu_f(fmaf(f, lsc[kbase + j], lsh[kbase + j]));
        raw[j] = f2bfbits(f);
      }
    }
    a[kk] = raw;
  }

  f32x4 acc[NT];
#pragma unroll
  for (int nt = 0; nt < NT; ++nt) acc[nt] = (f32x4){0.f, 0.f, 0.f, 0.f};

#pragma unroll
  for (int nt = 0; nt < NT; ++nt) {
    const short* brow = (const short*)&lw[(nt * 16 + lr) * LPR] + lg * 8;
#pragma unroll
    for (int kk = 0; kk < KK; ++kk) {
      short8v b = *(const short8v*)(brow + kk * 32);
      acc[nt] = __builtin_amdgcn_mfma_f32_16x16x32_bf16(a[kk], b, acc[nt], 0, 0, 0);
    }
  }

  int orow = m0 + (lg << 2);
#pragma unroll
  for (int nt = 0; nt < NT; ++nt) {
    int col = nt * 16 + lr;
    float bi = bias[col];
    float s = 0.f, q = 0.f;
#pragma unroll
    for (int r = 0; r < 4; ++r) {
      float y = acc[nt][r] + bi;
      float yb;
      if constexpr (sizeof(OutT) == 2) {
        bf16 b = __float2bfloat16(y);
        out[(size_t)(orow + r) * NOUT + col] = b;
        yb = __bfloat162float(b);
      } else {
        out[(size_t)(orow + r) * NOUT + col] = y;
        yb = y;
      }
      if (BFC) out_bf[(size_t)(orow + r) * NOUT + col] = __float2bfloat16(y);
      if (OSTATS) { s += yb; q += yb * yb; }
    }
    if (OSTATS) {
      s += __shfl_xor(s, 16, 64); s += __shfl_xor(s, 32, 64);
      q += __shfl_xor(q, 16, 64); q += __shfl_xor(q, 32, 64);
      if (lg == 0) { ssum[wave][col] = s; sqsum[wave][col] = q; }
    }
  }
  if (OSTATS) {
    __syncthreads();
    int tid = threadIdx.x;
    if (tid < NOUT) {
      float s = ssum[0][tid] + ssum[1][tid] + ssum[2][tid] + ssum[3][tid];
      float q = sqsum[0][tid] + sqsum[1][tid] + sqsum[2][tid] + sqsum[3][tid];
      atomAddD(&st[tid], (double)s);
      atomAddD(&st[NOUT + tid], (double)q);
    }
  }
}

// ======================= fused aggregate + GEMM1 (+stats) =======================
// A-fragment built on the fly: row t of A = hb[t] + (t<N ? hb[vn]+sum_edges hb[src]
//                                                   : sum_graph hb[i]);  z1 = A @ W1 + b1
template <int K, int NOUT>   // K=96, NOUT=192
__global__ __launch_bounds__(256) void k_gemm_agg(const bf16* __restrict__ hb,
    const int* __restrict__ batch, const int* __restrict__ rs, const int* __restrict__ ssrc,
    const int* __restrict__ gstart, const bf16* __restrict__ Wt, const float* __restrict__ bias,
    bf16* __restrict__ out, double* __restrict__ st) {
  constexpr int KK  = K / 32;      // 3
  constexpr int NT  = NOUT / 16;   // 12
  constexpr int UPR = K / 8;
  constexpr int LPR = UPR + 1;
  __shared__ uint4 lw[NOUT * LPR];
  __shared__ float ssum[4][NOUT];
  __shared__ float sqsum[4][NOUT];

  const uint4* wv = (const uint4*)Wt;
  for (int u = threadIdx.x; u < NOUT * UPR; u += 256) {
    int row = u / UPR, colu = u - row * UPR;
    lw[row * LPR + colu] = wv[u];
  }
  __syncthreads();

  int wave = threadIdx.x >> 6, lane = threadIdx.x & 63;
  int m0 = (blockIdx.x * 4 + wave) * 16;
  int lr = lane & 15, lg = lane >> 4;
  int row = m0 + lr;
  int koff = lg * 8;

  float av[KK * 8];
#pragma unroll
  for (int t = 0; t < KK * 8; ++t) av[t] = 0.f;

  auto addRow = [&](int r) {
    const short* hr = (const short*)hb + (size_t)r * K + koff;
#pragma unroll
    for (int kk = 0; kk < KK; ++kk) {
      short8v v = *(const short8v*)(hr + kk * 32);
#pragma unroll
      for (int j = 0; j < 8; ++j) av[kk * 8 + j] += bfbits2f(v[j]);
    }
  };

  addRow(row);
  if (row < N_) {                       // wave-uniform: 16-row groups never straddle N_
    addRow(N_ + batch[row]);
    int e1 = rs[row + 1];
    for (int e = rs[row]; e < e1; ++e) addRow(ssrc[e]);
  } else {
    int g = row - N_;
    int i1 = gstart[g + 1];
    for (int i = gstart[g]; i < i1; ++i) addRow(i);
  }

  short8v a[KK];
#pragma unroll
  for (int kk = 0; kk < KK; ++kk)
#pragma unroll
    for (int j = 0; j < 8; ++j) a[kk][j] = f2bfbits(av[kk * 8 + j]);

  f32x4 acc[NT];
#pragma unroll
  for (int nt = 0; nt < NT; ++nt) acc[nt] = (f32x4){0.f, 0.f, 0.f, 0.f};

#pragma unroll
  for (int nt = 0; nt < NT; ++nt) {
    const short* brow = (const short*)&lw[(nt * 16 + lr) * LPR] + lg * 8;
#pragma unroll
    for (int kk = 0; kk < KK; ++kk) {
      short8v b = *(const short8v*)(brow + kk * 32);
      acc[nt] = __builtin_amdgcn_mfma_f32_16x16x32_bf16(a[kk], b, acc[nt], 0, 0, 0);
    }
  }

  int orow = m0 + (lg << 2);
#pragma unroll
  for (int nt = 0; nt < NT; ++nt) {
    int col = nt * 16 + lr;
    float bi = bias[col];
    float s = 0.f, q = 0.f;
#pragma unroll
    for (int r = 0; r < 4; ++r) {
      float y = acc[nt][r] + bi;
      bf16 b = __float2bfloat16(y);
      out[(size_t)(orow + r) * NOUT + col] = b;
      float yb = __bfloat162float(b);
      s += yb; q += yb * yb;
    }
    s += __shfl_xor(s, 16, 64); s += __shfl_xor(s, 32, 64);
    q += __shfl_xor(q, 16, 64); q += __shfl_xor(q, 32, 64);
    if (lg == 0) { ssum[wave][col] = s; sqsum[wave][col] = q; }
  }
  __syncthreads();
  int tid = threadIdx.x;
  if (tid < NOUT) {
    float s = ssum[0][tid] + ssum[1][tid] + ssum[2][tid] + ssum[3][tid];
    float q = sqsum[0][tid] + sqsum[1][tid] + sqsum[2][tid] + sqsum[3][tid];
    atomAddD(&st[tid], (double)s);
    atomAddD(&st[NOUT + tid], (double)q);
  }
}

__global__ __launch_bounds__(256) void k_fill_vn(float* __restrict__ h, bf16* __restrict__ hb,
                                                 const float* __restrict__ vn) {
  int idx = blockIdx.x * 256 + threadIdx.x;
  if (idx >= G_ * C_) return;
  int c = idx % C_;
  float v = vn[c];
  h[(size_t)N_ * C_ + idx] = v;
  hb[(size_t)N_ * C_ + idx] = __float2bfloat16(v);
}

// ======================= BN helpers (VN / head only) =======================
template <int CC, typename T>
__global__ __launch_bounds__(256) void k_bnstats(const T* __restrict__ X, int R, double* __restrict__ st) {
  int c = threadIdx.x;
  float s = 0.f, q = 0.f;
  for (int r = blockIdx.x; r < R; r += gridDim.x) {
    float v = toF(X[(size_t)r * CC + c]);
    s += v;
    q += v * v;
  }
  atomAddD(&st[c], (double)s);
  atomAddD(&st[CC + c], (double)q);
}

template <int CC>
__global__ __launch_bounds__(256) void k_bnfin(const double* __restrict__ st, int R,
    const float* __restrict__ g, const float* __restrict__ be,
    float* __restrict__ scale, float* __restrict__ shift) {
  int c = threadIdx.x;
  if (c >= CC) return;
  double mean = st[c] / R;
  double var  = st[CC + c] / R - mean * mean;
  float sc = g[c] * rsqrtf((float)var + 1e-5f);
  scale[c] = sc;
  shift[c] = be[c] - (float)mean * sc;
}

template <int CC, typename T>
__global__ __launch_bounds__(256) void k_bnsilu(T* __restrict__ X, int R,
    const float* __restrict__ scale, const float* __restrict__ shift) {
  int idx = blockIdx.x * 256 + threadIdx.x;
  if (idx >= R * CC) return;
  int c = idx % CC;
  float y = fmaf(toF(X[idx]), scale[c], shift[c]);
  stv(&X[idx], silu_f(y));
}

// h = (resid ? h : 0) + silu(bn(Z)); also maintains bf16 shadow
__global__ __launch_bounds__(256) void k_update(const bf16* __restrict__ Z, float* __restrict__ h,
    bf16* __restrict__ hb, const float* __restrict__ scale, const float* __restrict__ shift,
    int addResid) {
  int idx = blockIdx.x * 256 + threadIdx.x;
  if (idx >= TOT_ * C_ / 4) return;
  int cg = idx % (C_ / 4);
  int c0 = cg * 4;
  short4 zv = ((const short4*)Z)[idx];
  float4 hv;
  if (addResid) hv = ((const float4*)h)[idx];
  float y0 = silu_f(fmaf(bfbits2f(zv.x), scale[c0 + 0], shift[c0 + 0]));
  float y1 = silu_f(fmaf(bfbits2f(zv.y), scale[c0 + 1], shift[c0 + 1]));
  float y2 = silu_f(fmaf(bfbits2f(zv.z), scale[c0 + 2], shift[c0 + 2]));
  float y3 = silu_f(fmaf(bfbits2f(zv.w), scale[c0 + 3], shift[c0 + 3]));
  float4 o;
  o.x = addResid ? hv.x + y0 : y0;
  o.y = addResid ? hv.y + y1 : y1;
  o.z = addResid ? hv.z + y2 : y2;
  o.w = addResid ? hv.w + y3 : y3;
  ((float4*)h)[idx] = o;
  short4 ob;
  ob.x = f2bfbits(o.x); ob.y = f2bfbits(o.y); ob.z = f2bfbits(o.z); ob.w = f2bfbits(o.w);
  ((short4*)hb)[idx] = ob;
}

// ======================= small fp32 matmul (VN + head) =======================
template <int K, int M, bool BFC>
__global__ __launch_bounds__(256) void k_mm(const float* __restrict__ A,
    const float* __restrict__ W, const float* __restrict__ bias,
    float* __restrict__ out, bf16* __restrict__ out_bf, int R) {
  int idx = blockIdx.x * 256 + threadIdx.x;
  if (idx >= R * M) return;
  int row = idx / M;
  int m   = idx - row * M;
  const float* ar = A + (size_t)row * K;
  float s = bias[m];
#pragma unroll 8
  for (int k = 0; k < K; ++k) s = fmaf(ar[k], W[k * M + m], s);
  out[idx] = s;
  if (BFC) out_bf[idx] = __float2bfloat16(s);
}

__global__ __launch_bounds__(256) void k_pool2(const float* __restrict__ h, const int* __restrict__ gstart,
                                               float* __restrict__ pooled) {
  int idx = blockIdx.x * 256 + threadIdx.x;
  if (idx >= G_ * C_) return;
  int g = idx / C_;
  int c = idx - g * C_;
  int i0 = gstart[g], i1 = gstart[g + 1];
  float s = 0.f;
  for (int i = i0; i < i1; ++i) s += h[(size_t)i * C_ + c];
  pooled[idx] = s / fmaxf((float)(i1 - i0), 1.0f);
}

static inline int gblk(long n) { return (int)((n + 255) / 256); }

extern "C" void kernel_launch(void* const* d_in, const int* in_sizes, int n_in,
                              void* d_out, int out_size, void* d_ws, size_t ws_size,
                              hipStream_t stream) {
  (void)in_sizes; (void)n_in; (void)out_size; (void)ws_size;
  const float* x       = (const float*)d_in[0];
  const int*   ei      = (const int*)d_in[1];
  const int*   batch   = (const int*)d_in[2];
  const float* enc_w   = (const float*)d_in[4];
  const float* enc_b   = (const float*)d_in[5];
  const float* vn_emb  = (const float*)d_in[6];
  const float* vn_w1   = (const float*)d_in[7];
  const float* vn_b1   = (const float*)d_in[8];
  const float* vn_g1   = (const float*)d_in[9];
  const float* vn_be1  = (const float*)d_in[10];
  const float* vn_w2   = (const float*)d_in[11];
  const float* vn_b2   = (const float*)d_in[12];
  const float* conv_w1 = (const float*)d_in[13];
  const float* conv_b1 = (const float*)d_in[14];
  const float* conv_g1 = (const float*)d_in[15];
  const float* conv_be1= (const float*)d_in[16];
  const float* conv_w2 = (const float*)d_in[17];
  const float* conv_b2 = (const float*)d_in[18];
  const float* bn_g    = (const float*)d_in[19];
  const float* bn_b    = (const float*)d_in[20];
  const float* h_w1    = (const float*)d_in[21];
  const float* h_b1    = (const float*)d_in[22];
  const float* h_g1    = (const float*)d_in[23];
  const float* h_be1   = (const float*)d_in[24];
  const float* h_w2    = (const float*)d_in[25];
  const float* h_b2    = (const float*)d_in[26];
  const float* h_g2    = (const float*)d_in[27];
  const float* h_be2   = (const float*)d_in[28];
  const float* h_w3    = (const float*)d_in[29];
  const float* h_b3    = (const float*)d_in[30];
  float* out = (float*)d_out;

  const int* e_src = ei;
  const int* e_tgt = ei + E_;

  char* p = (char*)d_ws;
  auto alloc = [&](size_t bytes) -> char* {
    char* r = p;
    p += (bytes + 15) & ~size_t(15);
    return r;
  };
  float*  h      = (float*) alloc((size_t)TOT_ * C_ * 4);
  bf16*   hbf    = (bf16*)  alloc((size_t)TOT_ * C_ * 2);
  float*  vt     = (float*) alloc((size_t)G_ * C_ * 4);
  float*  pooled = (float*) alloc((size_t)G_ * C_ * 4);
  float*  t1     = (float*) alloc((size_t)G_ * 48 * 4);
  float*  t2     = (float*) alloc((size_t)G_ * 24 * 4);
  float*  scale1 = (float*) alloc(256 * 4);
  float*  shift1 = (float*) alloc(256 * 4);
  float*  scale2 = (float*) alloc(256 * 4);
  float*  shift2 = (float*) alloc(256 * 4);
  double* st     = (double*)alloc(512 * 8);
  bf16*   z1     = (bf16*)  alloc((size_t)TOT_ * 2 * C_ * 2);
  bf16*   z2     = (bf16*)  alloc((size_t)TOT_ * C_ * 2);
  bf16*   xb     = (bf16*)  alloc((size_t)N_ * FIN_ * 2);
  bf16*   encwT  = (bf16*)  alloc((size_t)C_ * FIN_ * 2);
  bf16*   w1T    = (bf16*)  alloc((size_t)L_ * 2 * C_ * C_ * 2);
  bf16*   w2T    = (bf16*)  alloc((size_t)L_ * C_ * 2 * C_ * 2);
  int*    deg    = (int*)   alloc((size_t)N_ * 4);
  int*    cur    = (int*)   alloc((size_t)N_ * 4);
  int*    rs     = (int*)   alloc((size_t)(N_ + 1) * 4);
  int*    bsum   = (int*)   alloc(512 * 4);
  int*    boff   = (int*)   alloc(512 * 4);
  int*    ssrc   = (int*)   alloc((size_t)E_ * 4);
  int*    gstart = (int*)   alloc((size_t)(G_ + 1) * 4);

  // ---- preprocessing ----
  k_cast_x<<<gblk((long)N_ * FIN_), 256, 0, stream>>>(x, xb);
  k_transT<<<gblk((long)FIN_ * C_), 256, 0, stream>>>(enc_w, encwT, FIN_, C_, FIN_ * C_);
  k_transT<<<gblk((long)L_ * C_ * 2 * C_), 256, 0, stream>>>(conv_w1, w1T, C_, 2 * C_, L_ * C_ * 2 * C_);
  k_transT<<<gblk((long)L_ * 2 * C_ * C_), 256, 0, stream>>>(conv_w2, w2T, 2 * C_, C_, L_ * 2 * C_ * C_);

  hipMemsetAsync(deg, 0, (size_t)N_ * 4, stream);
  hipMemsetAsync(cur, 0, (size_t)N_ * 4, stream);
  k_deg_count<<<gblk(E_), 256, 0, stream>>>(e_tgt, deg);
  k_scan_local<<<N_ / 256, 256, 0, stream>>>(deg, rs, bsum);
  k_scan_bsum<<<1, 512, 0, stream>>>(bsum, boff);
  k_scan_add<<<gblk(N_ + 1), 256, 0, stream>>>(rs, boff);
  k_csr_fill<<<gblk(E_), 256, 0, stream>>>(e_src, e_tgt, rs, cur, ssrc);
  k_gbounds<<<gblk(N_ + 1), 256, 0, stream>>>(batch, gstart);

  // ---- encoder (writes fp32 h + bf16 shadow) + VN init ----
  k_gemm<FIN_, C_, false, false, true, float><<<N_ / 64, 256, 0, stream>>>(
      xb, encwT, enc_b, nullptr, nullptr, h, hbf, nullptr);
  k_fill_vn<<<gblk((long)G_ * C_), 256, 0, stream>>>(h, hbf, vn_emb);

  // ---- 8 conv layers ----
  for (int i = 0; i < L_; ++i) {
    const bf16*  wt1 = w1T + (size_t)i * 2 * C_ * C_;
    const bf16*  wt2 = w2T + (size_t)i * C_ * 2 * C_;
    const float* b1  = conv_b1 + (size_t)i * 2 * C_;
    const float* g1  = conv_g1 + (size_t)i * 2 * C_;
    const float* be1 = conv_be1+ (size_t)i * 2 * C_;
    const float* b2  = conv_b2 + (size_t)i * C_;
    const float* bg  = bn_g    + (size_t)i * C_;
    const float* bb  = bn_b    + (size_t)i * C_;

    // z1 = (h + agg) @ w1 + b1, aggregation fused into fragment build; stats fused
    hipMemsetAsync(st, 0, 384 * sizeof(double), stream);
    k_gemm_agg<C_, 2 * C_><<<TOT_ / 64, 256, 0, stream>>>(
        hbf, batch, rs, ssrc, gstart, wt1, b1, z1, st);
    k_bnfin<2 * C_><<<1, 2 * C_, 0, stream>>>(st, TOT_, g1, be1, scale1, shift1);

    // z2 = silu(bn(z1)) @ w2 + b2  (BN+SiLU fused on input, stats fused on output)
    hipMemsetAsync(st, 0, 384 * sizeof(double), stream);
    k_gemm<2 * C_, C_, true, true, false, bf16><<<TOT_ / 64, 256, 0, stream>>>(
        z1, wt2, b2, scale1, shift1, z2, nullptr, st);
    k_bnfin<C_><<<1, C_, 0, stream>>>(st, TOT_, bg, bb, scale2, shift2);

    k_update<<<gblk((long)TOT_ * C_ / 4), 256, 0, stream>>>(z2, h, hbf, scale2, shift2, i > 0);

    if (i < L_ - 1) {
      k_mm<C_, C_, false><<<gblk((long)G_ * C_), 256, 0, stream>>>(
          h + (size_t)N_ * C_, vn_w1, vn_b1, vt, nullptr, G_);
      hipMemsetAsync(st, 0, 384 * sizeof(double), stream);
      k_bnstats<C_, float><<<64, C_, 0, stream>>>(vt, G_, st);
      k_bnfin<C_><<<1, C_, 0, stream>>>(st, G_, vn_g1, vn_be1, scale1, shift1);
      k_bnsilu<C_, float><<<gblk((long)G_ * C_), 256, 0, stream>>>(vt, G_, scale1, shift1);
      k_mm<C_, C_, true><<<gblk((long)G_ * C_), 256, 0, stream>>>(
          vt, vn_w2, vn_b2, h + (size_t)N_ * C_, hbf + (size_t)N_ * C_, G_);
    }
  }

  // ---- mean pool ----
  k_pool2<<<gblk((long)G_ * C_), 256, 0, stream>>>(h, gstart, pooled);

  // ---- head MLP ----
  k_mm<C_, 48, false><<<gblk((long)G_ * 48), 256, 0, stream>>>(pooled, h_w1, h_b1, t1, nullptr, G_);
  hipMemsetAsync(st, 0, 384 * sizeof(double), stream);
  k_bnstats<48, float><<<64, 48, 0, stream>>>(t1, G_, st);
  k_bnfin<48><<<1, 48, 0, stream>>>(st, G_, h_g1, h_be1, scale1, shift1);
  k_bnsilu<48, float><<<gblk((long)G_ * 48), 256, 0, stream>>>(t1, G_, scale1, shift1);

  k_mm<48, 24, false><<<gblk((long)G_ * 24), 256, 0, stream>>>(t1, h_w2, h_b2, t2, nullptr, G_);
  hipMemsetAsync(st, 0, 384 * sizeof(double), stream);
  k_bnstats<24, float><<<64, 24, 0, stream>>>(t2, G_, st);
  k_bnfin<24><<<1, 24, 0, stream>>>(st, G_, h_g2, h_be2, scale1, shift1);
  k_bnsilu<24, float><<<gblk((long)G_ * 24), 256, 0, stream>>>(t2, G_, scale1, shift1);

  k_mm<24, 5, false><<<gblk((long)G_ * 5), 256, 0, stream>>>(t2, h_w3, h_b3, out, nullptr, G_);
}